// Round 8
// baseline (463.862 us; speedup 1.0000x reference)
//
#include <hip/hip_runtime.h>

#define N_NODES 50000
#define N_EDGES 400000
#define E_TOT   450000   // + self loops
#define NEG 0.2f
#define NB_SCAN ((N_NODES + 255) / 256)   // 196 blocks
#define MAXD 64                            // LDS-cached edges per node (P(deg>64) ~ 0)

typedef unsigned short ushort_t;
typedef __attribute__((ext_vector_type(8))) _Float16 half8;  // MFMA A/B frag (4 VGPRs)
typedef __attribute__((ext_vector_type(4))) float  f32x4;    // MFMA C/D frag
typedef __attribute__((ext_vector_type(8))) unsigned short ushort8;

__device__ __forceinline__ ushort_t f2h(float f){
    _Float16 h = (_Float16)f;
    union { _Float16 h; ushort_t u; } v; v.h = h; return v.u;
}
__device__ __forceinline__ float h_lo(unsigned u){
    union { unsigned u; _Float16 h[2]; } v; v.u = u; return (float)v.h[0];
}
__device__ __forceinline__ float h_hi(unsigned u){
    union { unsigned u; _Float16 h[2]; } v; v.u = u; return (float)v.h[1];
}
__device__ __forceinline__ void gload_lds16(const void* g, void* l){
    __builtin_amdgcn_global_load_lds((const __attribute__((address_space(1))) void*)g,
                                     (__attribute__((address_space(3))) void*)l, 16, 0, 0);
}
__device__ __forceinline__ int wave_incl_scan(int v, int lane){
    #pragma unroll
    for(int off = 1; off < 64; off <<= 1){
        int t = __shfl_up(v, off, 64);
        if(lane >= off) v += t;
    }
    return v;
}

// ---------------- graph build ----------------

__global__ void zero_ints(int* p, int n){
    int i = blockIdx.x*256 + threadIdx.x;
    if(i < n) p[i] = 0;
}

__global__ void count_deg(const int* __restrict__ ei, int* __restrict__ deg){
    int e = blockIdx.x*256 + threadIdx.x;
    if(e >= E_TOT) return;
    int dst = (e < N_EDGES) ? ei[N_EDGES + e] : (e - N_EDGES);
    atomicAdd(&deg[dst], 1);
}

__global__ void deg_block_sum(const int* __restrict__ deg, int* __restrict__ bsum){
    int i = blockIdx.x*256 + threadIdx.x;
    int lane = threadIdx.x & 63, wave = threadIdx.x >> 6;
    int v = (i < N_NODES) ? deg[i] : 0;
    #pragma unroll
    for(int off = 1; off < 64; off <<= 1) v += __shfl_xor(v, off, 64);
    __shared__ int sw[4];
    if(lane == 0) sw[wave] = v;
    __syncthreads();
    if(threadIdx.x == 0) bsum[blockIdx.x] = sw[0] + sw[1] + sw[2] + sw[3];
}

__global__ void scan_bsum(int* __restrict__ bsum, int* __restrict__ rowptr){
    int lane = threadIdx.x & 63, wave = threadIdx.x >> 6;
    int v = (threadIdx.x < NB_SCAN) ? bsum[threadIdx.x] : 0;
    int incl = wave_incl_scan(v, lane);
    __shared__ int sw[4];
    if(lane == 63) sw[wave] = incl;
    __syncthreads();
    int add = 0;
    for(int w = 0; w < wave; w++) add += sw[w];
    int excl = incl - v + add;
    if(threadIdx.x < NB_SCAN) bsum[threadIdx.x] = excl;
    if(threadIdx.x == 255) rowptr[N_NODES] = excl + v;
}

__global__ void scan_apply(const int* __restrict__ bsum,
                           int* __restrict__ dw, int* __restrict__ rowptr){
    int i = blockIdx.x*256 + threadIdx.x;
    int lane = threadIdx.x & 63, wave = threadIdx.x >> 6;
    int v = (i < N_NODES) ? dw[i] : 0;
    int incl = wave_incl_scan(v, lane);
    __shared__ int sw[4];
    if(lane == 63) sw[wave] = incl;
    __syncthreads();
    int add = bsum[blockIdx.x];
    for(int w = 0; w < wave; w++) add += sw[w];
    int excl = incl - v + add;
    if(i < N_NODES){ rowptr[i] = excl; dw[i] = excl; }
}

__global__ void scatter_edges(const int* __restrict__ ei, int* __restrict__ wofs,
                              int* __restrict__ csr){
    int e = blockIdx.x*256 + threadIdx.x;
    if(e >= E_TOT) return;
    int src, dst;
    if(e < N_EDGES){ src = ei[e]; dst = ei[N_EDGES + e]; }
    else { src = dst = e - N_EDGES; }
    int pos = atomicAdd(&wofs[dst], 1);
    csr[pos] = src;
}

// ---------------- fused fp32 -> f16 conversions (x, W0^T, W1^T) ----------------

__global__ void cvt_all(const float* __restrict__ x, const float* __restrict__ W0,
                        const float* __restrict__ W1,
                        ushort_t* __restrict__ xbf, ushort_t* __restrict__ W0t,
                        ushort_t* __restrict__ W1t){
    int i = blockIdx.x*256 + threadIdx.x;
    if(i < N_NODES*128) xbf[i] = f2h(x[i]);
    if(i < 512*128){ int n = i >> 7, k = i & 127; W0t[i] = f2h(W0[(size_t)k*512 + n]); }
    if(i < 512*512){ int n = i >> 9, k = i & 511; W1t[i] = f2h(W1[(size_t)k*512 + n]); }
}

// ---------------- f16 MFMA GEMM + fused attention logits ----------------
// Cb[M,512](f16) = A[M,K] @ Bt[512,K]^T ; als/ald[M,8] from fp32 acc, 16-lane reduce.

template<int K>
__global__ __launch_bounds__(256) void gemm_bt(const ushort_t* __restrict__ A,
                                               const ushort_t* __restrict__ Bt,
                                               ushort_t* __restrict__ Cb,
                                               const float* __restrict__ a_s,
                                               const float* __restrict__ a_d,
                                               float* __restrict__ als,
                                               float* __restrict__ ald, int M){
    __shared__ ushort_t As[128*32];
    __shared__ ushort_t Bs[128*32];
    int tid  = threadIdx.x;
    int wave = tid >> 6, lane = tid & 63;
    int wm = wave & 1, wn = wave >> 1;
    int row0 = blockIdx.y * 128;
    int col0 = blockIdx.x * 128;

    f32x4 acc[4][4] = {};

    int lrow = lane >> 2;
    int lchk = (lane & 3) * 8;

    for(int kt = 0; kt < K; kt += 32){
        #pragma unroll
        for(int s = 0; s < 2; s++){
            int seg = wave*2 + s;
            int ar = row0 + seg*16 + lrow;
            ar = ar < M ? ar : M-1;
            gload_lds16(A  + (size_t)ar*K + kt + lchk, As + seg*512);
            int br = col0 + seg*16 + lrow;
            gload_lds16(Bt + (size_t)br*K + kt + lchk, Bs + seg*512);
        }
        __syncthreads();

        half8 a[4], b[4];
        int fm = lane & 15, fq = (lane >> 4) * 8;
        #pragma unroll
        for(int t = 0; t < 4; t++){
            a[t] = *(const half8*)&As[(wm*64 + t*16 + fm)*32 + fq];
            b[t] = *(const half8*)&Bs[(wn*64 + t*16 + fm)*32 + fq];
        }
        #pragma unroll
        for(int i = 0; i < 4; i++)
            #pragma unroll
            for(int j = 0; j < 4; j++)
                acc[i][j] = __builtin_amdgcn_mfma_f32_16x16x32_f16(a[i], b[j], acc[i][j], 0, 0, 0);
        __syncthreads();
    }

    // epilogue: store f16 C + fused logits
    int cm = (lane >> 4) * 4, cn = lane & 15;
    int head = (col0 + wn*64) >> 6;           // uniform per wave
    float as_[4], ad_[4];
    #pragma unroll
    for(int j = 0; j < 4; j++){
        int c = head*64 + cn + j*16;
        as_[j] = a_s[c]; ad_[j] = a_d[c];
    }
    #pragma unroll
    for(int i = 0; i < 4; i++){
        #pragma unroll
        for(int p = 0; p < 4; p++){
            int r = row0 + wm*64 + i*16 + cm + p;   // uniform across 16-lane group
            float ps = 0.f, pd = 0.f;
            if(r < M){
                ushort_t* cp = &Cb[(size_t)r*512 + col0 + wn*64 + cn];
                #pragma unroll
                for(int j = 0; j < 4; j++){
                    float v = acc[i][j][p];
                    cp[j*16] = f2h(v);
                    ps += v*as_[j]; pd += v*ad_[j];
                }
            }
            #pragma unroll
            for(int off = 1; off < 16; off <<= 1){
                ps += __shfl_xor(ps, off);
                pd += __shfl_xor(pd, off);
            }
            if(cn == 0 && r < M){ als[r*8 + head] = ps; ald[r*8 + head] = pd; }
        }
    }
}

// ---------------- edge softmax + aggregation (f16 h gather), bias + ELU, f16 out ----------------
// one wave per node; per-edge exp cached in LDS (phase A), phase B = pure gather+FMA.

__global__ __launch_bounds__(256) void attn_agg(const ushort_t* __restrict__ h,
        const float* __restrict__ als, const float* __restrict__ ald,
        const int* __restrict__ rowptr, const int* __restrict__ csr,
        const float* __restrict__ bias, ushort_t* __restrict__ out){
    __shared__ float sm[4][8], sd[4][8];
    __shared__ float sex[4][MAXD][8];   // per-edge exp numerators, 8 KB
    int wv = threadIdx.x >> 6, lane = threadIdx.x & 63;
    int n = blockIdx.x*4 + wv;
    int start = rowptr[n], end = rowptr[n+1];

    int hd = lane & 7, e8 = lane >> 3;
    float aldv = ald[n*8 + hd];
    float lmax = -1e30f;
    for(int idx = start + e8; idx < end; idx += 8){
        int e = idx - start;
        int src = csr[idx];
        float v = als[src*8 + hd] + aldv;
        v = v > 0.f ? v : NEG*v;
        if(e < MAXD) sex[wv][e][hd] = v;
        lmax = fmaxf(lmax, v);
    }
    for(int off = 8; off < 64; off <<= 1) lmax = fmaxf(lmax, __shfl_xor(lmax, off));
    float lsum = 0.f;
    for(int idx = start + e8; idx < end; idx += 8){
        int e = idx - start;
        float v;
        if(e < MAXD) v = sex[wv][e][hd];
        else { int src = csr[idx]; v = als[src*8 + hd] + aldv; v = v > 0.f ? v : NEG*v; }
        float ex = __expf(v - lmax);
        if(e < MAXD) sex[wv][e][hd] = ex;
        lsum += ex;
    }
    for(int off = 8; off < 64; off <<= 1) lsum += __shfl_xor(lsum, off);
    if(lane < 8){ sm[wv][hd] = lmax; sd[wv][hd] = 1.f / lsum; }
    __syncthreads();

    int head = lane >> 3;
    float inv = sd[wv][head];
    float acc[8] = {};

    int cnt = end - start;
    int nmain = cnt < MAXD ? cnt : MAXD;
    int mend = start + nmain;
    int last = mend - 1;
    for(int idx = start; idx < mend; idx += 4){
        int j1 = idx+1, j2 = idx+2, j3 = idx+3;
        int s0 = csr[idx];
        int s1 = csr[j1 <= last ? j1 : last];
        int s2 = csr[j2 <= last ? j2 : last];
        int s3 = csr[j3 <= last ? j3 : last];
        uint4 p0 = *(const uint4*)&h[(size_t)s0*512 + lane*8];
        uint4 p1 = *(const uint4*)&h[(size_t)s1*512 + lane*8];
        uint4 p2 = *(const uint4*)&h[(size_t)s2*512 + lane*8];
        uint4 p3 = *(const uint4*)&h[(size_t)s3*512 + lane*8];
        float e0 = sex[wv][idx -start][head];
        float e1 = (j1 < mend) ? sex[wv][j1-start][head] : 0.f;
        float e2 = (j2 < mend) ? sex[wv][j2-start][head] : 0.f;
        float e3 = (j3 < mend) ? sex[wv][j3-start][head] : 0.f;
        acc[0] += e0*h_lo(p0.x) + e1*h_lo(p1.x) + e2*h_lo(p2.x) + e3*h_lo(p3.x);
        acc[1] += e0*h_hi(p0.x) + e1*h_hi(p1.x) + e2*h_hi(p2.x) + e3*h_hi(p3.x);
        acc[2] += e0*h_lo(p0.y) + e1*h_lo(p1.y) + e2*h_lo(p2.y) + e3*h_lo(p3.y);
        acc[3] += e0*h_hi(p0.y) + e1*h_hi(p1.y) + e2*h_hi(p2.y) + e3*h_hi(p3.y);
        acc[4] += e0*h_lo(p0.z) + e1*h_lo(p1.z) + e2*h_lo(p2.z) + e3*h_lo(p3.z);
        acc[5] += e0*h_hi(p0.z) + e1*h_hi(p1.z) + e2*h_hi(p2.z) + e3*h_hi(p3.z);
        acc[6] += e0*h_lo(p0.w) + e1*h_lo(p1.w) + e2*h_lo(p2.w) + e3*h_lo(p3.w);
        acc[7] += e0*h_hi(p0.w) + e1*h_hi(p1.w) + e2*h_hi(p2.w) + e3*h_hi(p3.w);
    }
    // rare tail: deg > MAXD, recompute alpha
    if(mend < end){
        float m = sm[wv][head];
        float aldn = ald[n*8 + head];
        for(int idx = mend; idx < end; idx++){
            int src = csr[idx];
            float v = als[src*8 + head] + aldn;
            v = v > 0.f ? v : NEG*v;
            float e0 = __expf(v - m);
            uint4 p = *(const uint4*)&h[(size_t)src*512 + lane*8];
            acc[0] += e0*h_lo(p.x); acc[1] += e0*h_hi(p.x);
            acc[2] += e0*h_lo(p.y); acc[3] += e0*h_hi(p.y);
            acc[4] += e0*h_lo(p.z); acc[5] += e0*h_hi(p.z);
            acc[6] += e0*h_lo(p.w); acc[7] += e0*h_hi(p.w);
        }
    }

    ushort8 o;
    #pragma unroll
    for(int j = 0; j < 8; j++){
        float v = acc[j]*inv + bias[lane*8 + j];
        v = v > 0.f ? v : (__expf(v) - 1.f);   // ELU
        o[j] = f2h(v);
    }
    *(ushort8*)&out[(size_t)n*512 + lane*8] = o;
}

// ---------------- layer 2: GEMM [N,512](f16) x [512,16](f32) + fused logits2 ----------------

__global__ __launch_bounds__(256) void gemm2_k(const ushort_t* __restrict__ A,
                                               const float* __restrict__ W,
                                               const float* __restrict__ a_s2,
                                               const float* __restrict__ a_d2,
                                               float* __restrict__ C,
                                               float* __restrict__ als,
                                               float* __restrict__ ald){
    __shared__ float Ws[16][513];
    for(int i = threadIdx.x; i < 512*16; i += 256){
        int k = i >> 4, c = i & 15;
        Ws[c][k] = W[i];
    }
    __syncthreads();
    int t = blockIdx.x*256 + threadIdx.x;
    int c = t & 15;
    long row = t >> 4;
    const ushort_t* ap = &A[row*512];
    const float* wp = &Ws[c][0];
    float acc = 0.f;
    for(int k = 0; k < 512; k += 8){
        uint4 p = *(const uint4*)&ap[k];
        acc += h_lo(p.x)*wp[k+0] + h_hi(p.x)*wp[k+1]
             + h_lo(p.y)*wp[k+2] + h_hi(p.y)*wp[k+3]
             + h_lo(p.z)*wp[k+4] + h_hi(p.z)*wp[k+5]
             + h_lo(p.w)*wp[k+6] + h_hi(p.w)*wp[k+7];
    }
    C[t] = acc;
    // fused logits2: threads c=0..15 of the same row form one 16-lane group
    float ps = acc * a_s2[c], pd = acc * a_d2[c];
    #pragma unroll
    for(int off = 1; off < 16; off <<= 1){
        ps += __shfl_xor(ps, off);
        pd += __shfl_xor(pd, off);
    }
    if(c == 0){ als[row] = ps; ald[row] = pd; }
}

// final layer agg: 16 lanes per node, 4 nodes per wave, 16 nodes per block
__global__ __launch_bounds__(256) void attn_agg2(const float* __restrict__ h2,
        const float* __restrict__ als, const float* __restrict__ ald,
        const int* __restrict__ rowptr, const int* __restrict__ csr,
        const float* __restrict__ b2, float* __restrict__ out){
    int wv = threadIdx.x >> 6, lane = threadIdx.x & 63;
    int q = lane >> 4, c = lane & 15;
    int n = blockIdx.x*16 + wv*4 + q;
    int start = rowptr[n], end = rowptr[n+1];
    float aldv = ald[n];

    float lmax = -1e30f;
    for(int idx = start + c; idx < end; idx += 16){
        float v = als[csr[idx]] + aldv; v = v > 0.f ? v : NEG*v;
        lmax = fmaxf(lmax, v);
    }
    #pragma unroll
    for(int off = 1; off < 16; off <<= 1) lmax = fmaxf(lmax, __shfl_xor(lmax, off));
    float lsum = 0.f;
    for(int idx = start + c; idx < end; idx += 16){
        float v = als[csr[idx]] + aldv; v = v > 0.f ? v : NEG*v;
        lsum += __expf(v - lmax);
    }
    #pragma unroll
    for(int off = 1; off < 16; off <<= 1) lsum += __shfl_xor(lsum, off);
    float inv = 1.f / lsum;

    float acc = 0.f;
    for(int idx = start; idx < end; idx++){
        int src = csr[idx];
        float v = als[src] + aldv; v = v > 0.f ? v : NEG*v;
        float alpha = __expf(v - lmax) * inv;
        acc += alpha * h2[src*16 + c];
    }
    out[n*16 + c] = acc + b2[c];
}

// ---------------- launch ----------------

extern "C" void kernel_launch(void* const* d_in, const int* in_sizes, int n_in,
                              void* d_out, int out_size, void* d_ws, size_t ws_size,
                              hipStream_t stream) {
    const float* x    = (const float*)d_in[0];
    const int*   ei   = (const int*)  d_in[1];
    const float* W0   = (const float*)d_in[2];
    const float* a_s0 = (const float*)d_in[3];
    const float* a_d0 = (const float*)d_in[4];
    const float* b0   = (const float*)d_in[5];
    const float* W1   = (const float*)d_in[6];
    const float* a_s1 = (const float*)d_in[7];
    const float* a_d1 = (const float*)d_in[8];
    const float* b1   = (const float*)d_in[9];
    const float* W2   = (const float*)d_in[10];
    const float* a_s2 = (const float*)d_in[11];
    const float* a_d2 = (const float*)d_in[12];
    const float* b2   = (const float*)d_in[13];
    float* out = (float*)d_out;

    char* w = (char*)d_ws;
    auto alloc = [&](size_t bytes){ void* p = (void*)w; w += (bytes + 255) & ~(size_t)255; return p; };
    int*      rowptr = (int*)     alloc((N_NODES+1)*sizeof(int));
    int*      wofs   = (int*)     alloc(N_NODES*sizeof(int));
    int*      bsum   = (int*)     alloc(NB_SCAN*sizeof(int));
    int*      csr    = (int*)     alloc(E_TOT*sizeof(int));
    float*    als    = (float*)   alloc((size_t)N_NODES*8*sizeof(float));
    float*    ald    = (float*)   alloc((size_t)N_NODES*8*sizeof(float));
    ushort_t* hb     = (ushort_t*)alloc((size_t)N_NODES*512*sizeof(ushort_t));
    ushort_t* hbf    = (ushort_t*)alloc((size_t)N_NODES*512*sizeof(ushort_t));
    ushort_t* xbf    = (ushort_t*)alloc((size_t)N_NODES*128*sizeof(ushort_t));
    ushort_t* W0t    = (ushort_t*)alloc((size_t)512*128*sizeof(ushort_t));
    ushort_t* W1t    = (ushort_t*)alloc((size_t)512*512*sizeof(ushort_t));
    float*    h2     = (float*)   alloc((size_t)N_NODES*16*sizeof(float));

    // graph build: count -> hierarchical scan -> scatter
    zero_ints<<<(N_NODES+255)/256, 256, 0, stream>>>(wofs, N_NODES);
    count_deg<<<(E_TOT+255)/256, 256, 0, stream>>>(ei, wofs);
    deg_block_sum<<<NB_SCAN, 256, 0, stream>>>(wofs, bsum);
    scan_bsum<<<1, 256, 0, stream>>>(bsum, rowptr);
    scan_apply<<<NB_SCAN, 256, 0, stream>>>(bsum, wofs, rowptr);
    scatter_edges<<<(E_TOT+255)/256, 256, 0, stream>>>(ei, wofs, csr);

    // fused f16 conversions
    cvt_all<<<(N_NODES*128+255)/256, 256, 0, stream>>>(x, W0, W1, xbf, W0t, W1t);

    // layer 0 (logits fused into gemm epilogue)
    gemm_bt<128><<<dim3(4, (N_NODES+127)/128), 256, 0, stream>>>(xbf, W0t, hb, a_s0, a_d0, als, ald, N_NODES);
    attn_agg<<<N_NODES/4, 256, 0, stream>>>(hb, als, ald, rowptr, csr, b0, hbf);

    // layer 1
    gemm_bt<512><<<dim3(4, (N_NODES+127)/128), 256, 0, stream>>>(hbf, W1t, hb, a_s1, a_d1, als, ald, N_NODES);
    attn_agg<<<N_NODES/4, 256, 0, stream>>>(hb, als, ald, rowptr, csr, b1, hbf);

    // layer 2 (logits2 fused)
    gemm2_k<<<(N_NODES*16)/256, 256, 0, stream>>>(hbf, W2, a_s2, a_d2, h2, als, ald);
    attn_agg2<<<N_NODES/16, 256, 0, stream>>>(h2, als, ald, rowptr, csr, b2, out);
}

// Round 9
// 460.655 us; speedup vs baseline: 1.0070x; 1.0070x over previous
//
#include <hip/hip_runtime.h>

#define N_NODES 50000
#define N_EDGES 400000
#define E_TOT   450000   // + self loops
#define NEG 0.2f
#define NB_SCAN ((N_NODES + 255) / 256)   // 196 blocks
#define MAXD 64                            // LDS-cached edges per node (P(deg>64) ~ 0)

typedef unsigned short ushort_t;
typedef __attribute__((ext_vector_type(8))) _Float16 half8;  // MFMA A/B frag (4 VGPRs)
typedef __attribute__((ext_vector_type(4))) float  f32x4;    // MFMA C/D frag
typedef __attribute__((ext_vector_type(8))) unsigned short ushort8;

__device__ __forceinline__ ushort_t f2h(float f){
    _Float16 h = (_Float16)f;
    union { _Float16 h; ushort_t u; } v; v.h = h; return v.u;
}
__device__ __forceinline__ float h_lo(unsigned u){
    union { unsigned u; _Float16 h[2]; } v; v.u = u; return (float)v.h[0];
}
__device__ __forceinline__ float h_hi(unsigned u){
    union { unsigned u; _Float16 h[2]; } v; v.u = u; return (float)v.h[1];
}
__device__ __forceinline__ void gload_lds16(const void* g, void* l){
    __builtin_amdgcn_global_load_lds((const __attribute__((address_space(1))) void*)g,
                                     (__attribute__((address_space(3))) void*)l, 16, 0, 0);
}
__device__ __forceinline__ int wave_incl_scan(int v, int lane){
    #pragma unroll
    for(int off = 1; off < 64; off <<= 1){
        int t = __shfl_up(v, off, 64);
        if(lane >= off) v += t;
    }
    return v;
}

// ---------------- graph build ----------------

__global__ void count_deg(const int* __restrict__ ei, int* __restrict__ deg){
    int e = blockIdx.x*256 + threadIdx.x;
    if(e >= E_TOT) return;
    int dst = (e < N_EDGES) ? ei[N_EDGES + e] : (e - N_EDGES);
    atomicAdd(&deg[dst], 1);
}

__global__ void deg_block_sum(const int* __restrict__ deg, int* __restrict__ bsum){
    int i = blockIdx.x*256 + threadIdx.x;
    int lane = threadIdx.x & 63, wave = threadIdx.x >> 6;
    int v = (i < N_NODES) ? deg[i] : 0;
    #pragma unroll
    for(int off = 1; off < 64; off <<= 1) v += __shfl_xor(v, off, 64);
    __shared__ int sw[4];
    if(lane == 0) sw[wave] = v;
    __syncthreads();
    if(threadIdx.x == 0) bsum[blockIdx.x] = sw[0] + sw[1] + sw[2] + sw[3];
}

// fused: each block computes its global offset from RAW bsum, then local scan
__global__ void scan_apply(const int* __restrict__ bsum,
                           int* __restrict__ dw, int* __restrict__ rowptr){
    __shared__ int soff;
    __shared__ int sw[4];
    int i = blockIdx.x*256 + threadIdx.x;
    int lane = threadIdx.x & 63, wave = threadIdx.x >> 6;
    // wave 0: offset = sum of bsum[0..blockIdx.x)
    if(wave == 0){
        int s = 0;
        for(int j = lane; j < (int)blockIdx.x; j += 64) s += bsum[j];
        #pragma unroll
        for(int off = 1; off < 64; off <<= 1) s += __shfl_xor(s, off, 64);
        if(lane == 0) soff = s;
    }
    int v = (i < N_NODES) ? dw[i] : 0;
    int incl = wave_incl_scan(v, lane);
    if(lane == 63) sw[wave] = incl;
    __syncthreads();
    int add = soff;
    for(int w = 0; w < wave; w++) add += sw[w];
    int excl = incl - v + add;
    if(i < N_NODES){ rowptr[i] = excl; dw[i] = excl; }
    if(i == N_NODES-1) rowptr[N_NODES] = excl + v;
}

__global__ void scatter_edges(const int* __restrict__ ei, int* __restrict__ wofs,
                              int* __restrict__ csr){
    int e = blockIdx.x*256 + threadIdx.x;
    if(e >= E_TOT) return;
    int src, dst;
    if(e < N_EDGES){ src = ei[e]; dst = ei[N_EDGES + e]; }
    else { src = dst = e - N_EDGES; }
    int pos = atomicAdd(&wofs[dst], 1);
    csr[pos] = src;
}

// ---------------- fused fp32 -> f16 conversions + zero wofs ----------------

__global__ void cvt_all(const float* __restrict__ x, const float* __restrict__ W0,
                        const float* __restrict__ W1,
                        ushort_t* __restrict__ xbf, ushort_t* __restrict__ W0t,
                        ushort_t* __restrict__ W1t, int* __restrict__ wofs){
    int i = blockIdx.x*256 + threadIdx.x;
    if(i < N_NODES*128) xbf[i] = f2h(x[i]);
    if(i < 512*128){ int n = i >> 7, k = i & 127; W0t[i] = f2h(W0[(size_t)k*512 + n]); }
    if(i < 512*512){ int n = i >> 9, k = i & 511; W1t[i] = f2h(W1[(size_t)k*512 + n]); }
    if(i < N_NODES) wofs[i] = 0;
}

// ---------------- f16 MFMA GEMM + fused attention logits ----------------

template<int K>
__global__ __launch_bounds__(256) void gemm_bt(const ushort_t* __restrict__ A,
                                               const ushort_t* __restrict__ Bt,
                                               ushort_t* __restrict__ Cb,
                                               const float* __restrict__ a_s,
                                               const float* __restrict__ a_d,
                                               float* __restrict__ als,
                                               float* __restrict__ ald, int M){
    __shared__ ushort_t As[128*32];
    __shared__ ushort_t Bs[128*32];
    int tid  = threadIdx.x;
    int wave = tid >> 6, lane = tid & 63;
    int wm = wave & 1, wn = wave >> 1;
    int row0 = blockIdx.y * 128;
    int col0 = blockIdx.x * 128;

    f32x4 acc[4][4] = {};

    int lrow = lane >> 2;
    int lchk = (lane & 3) * 8;

    for(int kt = 0; kt < K; kt += 32){
        #pragma unroll
        for(int s = 0; s < 2; s++){
            int seg = wave*2 + s;
            int ar = row0 + seg*16 + lrow;
            ar = ar < M ? ar : M-1;
            gload_lds16(A  + (size_t)ar*K + kt + lchk, As + seg*512);
            int br = col0 + seg*16 + lrow;
            gload_lds16(Bt + (size_t)br*K + kt + lchk, Bs + seg*512);
        }
        __syncthreads();

        half8 a[4], b[4];
        int fm = lane & 15, fq = (lane >> 4) * 8;
        #pragma unroll
        for(int t = 0; t < 4; t++){
            a[t] = *(const half8*)&As[(wm*64 + t*16 + fm)*32 + fq];
            b[t] = *(const half8*)&Bs[(wn*64 + t*16 + fm)*32 + fq];
        }
        #pragma unroll
        for(int i = 0; i < 4; i++)
            #pragma unroll
            for(int j = 0; j < 4; j++)
                acc[i][j] = __builtin_amdgcn_mfma_f32_16x16x32_f16(a[i], b[j], acc[i][j], 0, 0, 0);
        __syncthreads();
    }

    // epilogue: store f16 C + fused logits
    int cm = (lane >> 4) * 4, cn = lane & 15;
    int head = (col0 + wn*64) >> 6;
    float as_[4], ad_[4];
    #pragma unroll
    for(int j = 0; j < 4; j++){
        int c = head*64 + cn + j*16;
        as_[j] = a_s[c]; ad_[j] = a_d[c];
    }
    #pragma unroll
    for(int i = 0; i < 4; i++){
        #pragma unroll
        for(int p = 0; p < 4; p++){
            int r = row0 + wm*64 + i*16 + cm + p;
            float ps = 0.f, pd = 0.f;
            if(r < M){
                ushort_t* cp = &Cb[(size_t)r*512 + col0 + wn*64 + cn];
                #pragma unroll
                for(int j = 0; j < 4; j++){
                    float v = acc[i][j][p];
                    cp[j*16] = f2h(v);
                    ps += v*as_[j]; pd += v*ad_[j];
                }
            }
            #pragma unroll
            for(int off = 1; off < 16; off <<= 1){
                ps += __shfl_xor(ps, off);
                pd += __shfl_xor(pd, off);
            }
            if(cn == 0 && r < M){ als[r*8 + head] = ps; ald[r*8 + head] = pd; }
        }
    }
}

// ---------------- edge softmax + aggregation (f16 h gather), bias + ELU, f16 out ----------------
// one wave per node; per-edge exp cached in LDS; phase B masked 8-wide.

__global__ __launch_bounds__(256) void attn_agg(const ushort_t* __restrict__ h,
        const float* __restrict__ als, const float* __restrict__ ald,
        const int* __restrict__ rowptr, const int* __restrict__ csr,
        const float* __restrict__ bias, ushort_t* __restrict__ out){
    __shared__ float sm[4][8], sd[4][8];
    __shared__ float sex[4][MAXD][8];   // per-edge exp numerators, 8 KB
    int wv = threadIdx.x >> 6, lane = threadIdx.x & 63;
    int n = blockIdx.x*4 + wv;
    int start = rowptr[n], end = rowptr[n+1];

    int hd = lane & 7, e8 = lane >> 3;
    float aldv = ald[n*8 + hd];
    float lmax = -1e30f;
    for(int idx = start + e8; idx < end; idx += 8){
        int e = idx - start;
        int src = csr[idx];
        float v = als[src*8 + hd] + aldv;
        v = v > 0.f ? v : NEG*v;
        if(e < MAXD) sex[wv][e][hd] = v;
        lmax = fmaxf(lmax, v);
    }
    for(int off = 8; off < 64; off <<= 1) lmax = fmaxf(lmax, __shfl_xor(lmax, off));
    float lsum = 0.f;
    for(int idx = start + e8; idx < end; idx += 8){
        int e = idx - start;
        float v;
        if(e < MAXD) v = sex[wv][e][hd];
        else { int src = csr[idx]; v = als[src*8 + hd] + aldv; v = v > 0.f ? v : NEG*v; }
        float ex = __expf(v - lmax);
        if(e < MAXD) sex[wv][e][hd] = ex;
        lsum += ex;
    }
    for(int off = 8; off < 64; off <<= 1) lsum += __shfl_xor(lsum, off);
    if(lane < 8){ sm[wv][hd] = lmax; sd[wv][hd] = 1.f / lsum; }
    __syncthreads();

    int head = lane >> 3;
    float inv = sd[wv][head];
    float acc[8] = {};

    int cnt = end - start;
    int nmain = cnt < MAXD ? cnt : MAXD;
    int mend = start + nmain;
    int last = mend - 1;
    for(int idx = start; idx < mend; idx += 8){
        int ss[8]; uint4 pp[8]; float ee[8];
        #pragma unroll
        for(int k = 0; k < 8; k++){
            int j = idx + k;
            ss[k] = csr[j <= last ? j : last];
        }
        #pragma unroll
        for(int k = 0; k < 8; k++)
            pp[k] = *(const uint4*)&h[(size_t)ss[k]*512 + lane*8];
        #pragma unroll
        for(int k = 0; k < 8; k++){
            int j = idx + k;
            ee[k] = (j < mend) ? sex[wv][j-start][head] : 0.f;
        }
        #pragma unroll
        for(int k = 0; k < 8; k++){
            acc[0] += ee[k]*h_lo(pp[k].x); acc[1] += ee[k]*h_hi(pp[k].x);
            acc[2] += ee[k]*h_lo(pp[k].y); acc[3] += ee[k]*h_hi(pp[k].y);
            acc[4] += ee[k]*h_lo(pp[k].z); acc[5] += ee[k]*h_hi(pp[k].z);
            acc[6] += ee[k]*h_lo(pp[k].w); acc[7] += ee[k]*h_hi(pp[k].w);
        }
    }
    // rare tail: deg > MAXD, recompute alpha
    if(mend < end){
        float m = sm[wv][head];
        float aldn = ald[n*8 + head];
        for(int idx = mend; idx < end; idx++){
            int src = csr[idx];
            float v = als[src*8 + head] + aldn;
            v = v > 0.f ? v : NEG*v;
            float e0 = __expf(v - m);
            uint4 p = *(const uint4*)&h[(size_t)src*512 + lane*8];
            acc[0] += e0*h_lo(p.x); acc[1] += e0*h_hi(p.x);
            acc[2] += e0*h_lo(p.y); acc[3] += e0*h_hi(p.y);
            acc[4] += e0*h_lo(p.z); acc[5] += e0*h_hi(p.z);
            acc[6] += e0*h_lo(p.w); acc[7] += e0*h_hi(p.w);
        }
    }

    ushort8 o;
    #pragma unroll
    for(int j = 0; j < 8; j++){
        float v = acc[j]*inv + bias[lane*8 + j];
        v = v > 0.f ? v : (__expf(v) - 1.f);   // ELU
        o[j] = f2h(v);
    }
    *(ushort8*)&out[(size_t)n*512 + lane*8] = o;
}

// ---------------- layer 2: GEMM [N,512](f16) x [512,16](f32) + fused logits2 ----------------

__global__ __launch_bounds__(256) void gemm2_k(const ushort_t* __restrict__ A,
                                               const float* __restrict__ W,
                                               const float* __restrict__ a_s2,
                                               const float* __restrict__ a_d2,
                                               float* __restrict__ C,
                                               float* __restrict__ als,
                                               float* __restrict__ ald){
    __shared__ float Ws[16][513];
    for(int i = threadIdx.x; i < 512*16; i += 256){
        int k = i >> 4, c = i & 15;
        Ws[c][k] = W[i];
    }
    __syncthreads();
    int t = blockIdx.x*256 + threadIdx.x;
    int c = t & 15;
    long row = t >> 4;
    const ushort_t* ap = &A[row*512];
    const float* wp = &Ws[c][0];
    float acc = 0.f;
    for(int k = 0; k < 512; k += 8){
        uint4 p = *(const uint4*)&ap[k];
        acc += h_lo(p.x)*wp[k+0] + h_hi(p.x)*wp[k+1]
             + h_lo(p.y)*wp[k+2] + h_hi(p.y)*wp[k+3]
             + h_lo(p.z)*wp[k+4] + h_hi(p.z)*wp[k+5]
             + h_lo(p.w)*wp[k+6] + h_hi(p.w)*wp[k+7];
    }
    C[t] = acc;
    float ps = acc * a_s2[c], pd = acc * a_d2[c];
    #pragma unroll
    for(int off = 1; off < 16; off <<= 1){
        ps += __shfl_xor(ps, off);
        pd += __shfl_xor(pd, off);
    }
    if(c == 0){ als[row] = ps; ald[row] = pd; }
}

// final layer agg: 16 lanes per node, 4 nodes per wave, 16 nodes per block
__global__ __launch_bounds__(256) void attn_agg2(const float* __restrict__ h2,
        const float* __restrict__ als, const float* __restrict__ ald,
        const int* __restrict__ rowptr, const int* __restrict__ csr,
        const float* __restrict__ b2, float* __restrict__ out){
    int wv = threadIdx.x >> 6, lane = threadIdx.x & 63;
    int q = lane >> 4, c = lane & 15;
    int n = blockIdx.x*16 + wv*4 + q;
    int start = rowptr[n], end = rowptr[n+1];
    float aldv = ald[n];

    float lmax = -1e30f;
    for(int idx = start + c; idx < end; idx += 16){
        float v = als[csr[idx]] + aldv; v = v > 0.f ? v : NEG*v;
        lmax = fmaxf(lmax, v);
    }
    #pragma unroll
    for(int off = 1; off < 16; off <<= 1) lmax = fmaxf(lmax, __shfl_xor(lmax, off));
    float lsum = 0.f;
    for(int idx = start + c; idx < end; idx += 16){
        float v = als[csr[idx]] + aldv; v = v > 0.f ? v : NEG*v;
        lsum += __expf(v - lmax);
    }
    #pragma unroll
    for(int off = 1; off < 16; off <<= 1) lsum += __shfl_xor(lsum, off);
    float inv = 1.f / lsum;

    float acc = 0.f;
    for(int idx = start; idx < end; idx++){
        int src = csr[idx];
        float v = als[src] + aldv; v = v > 0.f ? v : NEG*v;
        float alpha = __expf(v - lmax) * inv;
        acc += alpha * h2[src*16 + c];
    }
    out[n*16 + c] = acc + b2[c];
}

// ---------------- launch ----------------

extern "C" void kernel_launch(void* const* d_in, const int* in_sizes, int n_in,
                              void* d_out, int out_size, void* d_ws, size_t ws_size,
                              hipStream_t stream) {
    const float* x    = (const float*)d_in[0];
    const int*   ei   = (const int*)  d_in[1];
    const float* W0   = (const float*)d_in[2];
    const float* a_s0 = (const float*)d_in[3];
    const float* a_d0 = (const float*)d_in[4];
    const float* b0   = (const float*)d_in[5];
    const float* W1   = (const float*)d_in[6];
    const float* a_s1 = (const float*)d_in[7];
    const float* a_d1 = (const float*)d_in[8];
    const float* b1   = (const float*)d_in[9];
    const float* W2   = (const float*)d_in[10];
    const float* a_s2 = (const float*)d_in[11];
    const float* a_d2 = (const float*)d_in[12];
    const float* b2   = (const float*)d_in[13];
    float* out = (float*)d_out;

    char* w = (char*)d_ws;
    auto alloc = [&](size_t bytes){ void* p = (void*)w; w += (bytes + 255) & ~(size_t)255; return p; };
    int*      rowptr = (int*)     alloc((N_NODES+1)*sizeof(int));
    int*      wofs   = (int*)     alloc(N_NODES*sizeof(int));
    int*      bsum   = (int*)     alloc(NB_SCAN*sizeof(int));
    int*      csr    = (int*)     alloc(E_TOT*sizeof(int));
    float*    als    = (float*)   alloc((size_t)N_NODES*8*sizeof(float));
    float*    ald    = (float*)   alloc((size_t)N_NODES*8*sizeof(float));
    ushort_t* hb     = (ushort_t*)alloc((size_t)N_NODES*512*sizeof(ushort_t));
    ushort_t* hbf    = (ushort_t*)alloc((size_t)N_NODES*512*sizeof(ushort_t));
    ushort_t* xbf    = (ushort_t*)alloc((size_t)N_NODES*128*sizeof(ushort_t));
    ushort_t* W0t    = (ushort_t*)alloc((size_t)512*128*sizeof(ushort_t));
    ushort_t* W1t    = (ushort_t*)alloc((size_t)512*512*sizeof(ushort_t));
    float*    h2     = (float*)   alloc((size_t)N_NODES*16*sizeof(float));

    // conversions + zero wofs (1 dispatch)
    cvt_all<<<(N_NODES*128+255)/256, 256, 0, stream>>>(x, W0, W1, xbf, W0t, W1t, wofs);

    // graph build: count -> block sums -> fused scan+apply -> scatter
    count_deg<<<(E_TOT+255)/256, 256, 0, stream>>>(ei, wofs);
    deg_block_sum<<<NB_SCAN, 256, 0, stream>>>(wofs, bsum);
    scan_apply<<<NB_SCAN, 256, 0, stream>>>(bsum, wofs, rowptr);
    scatter_edges<<<(E_TOT+255)/256, 256, 0, stream>>>(ei, wofs, csr);

    // layer 0 (logits fused into gemm epilogue)
    gemm_bt<128><<<dim3(4, (N_NODES+127)/128), 256, 0, stream>>>(xbf, W0t, hb, a_s0, a_d0, als, ald, N_NODES);
    attn_agg<<<N_NODES/4, 256, 0, stream>>>(hb, als, ald, rowptr, csr, b0, hbf);

    // layer 1
    gemm_bt<512><<<dim3(4, (N_NODES+127)/128), 256, 0, stream>>>(hbf, W1t, hb, a_s1, a_d1, als, ald, N_NODES);
    attn_agg<<<N_NODES/4, 256, 0, stream>>>(hb, als, ald, rowptr, csr, b1, hbf);

    // layer 2 (logits2 fused)
    gemm2_k<<<(N_NODES*16)/256, 256, 0, stream>>>(hbf, W2, a_s2, a_d2, h2, als, ald);
    attn_agg2<<<N_NODES/16, 256, 0, stream>>>(h2, als, ald, rowptr, csr, b2, out);
}